// Round 5
// baseline (604.220 us; speedup 1.0000x reference)
//
#include <hip/hip_runtime.h>
#include <hip/hip_cooperative_groups.h>
#include <cmath>

namespace cg = cooperative_groups;

#define B_ 8
#define C_ 64
#define M_ 256
#define N_ 256
#define PLANE_ 65536
#define PIX_ 524288
#define THRESH_ 0.8f
#define EPS_ 1e-5f
#define NBLK_ 512
#define NTHR_ 256
#define NTID_ (NBLK_*NTHR_)      // 131072

typedef float vfloat4 __attribute__((ext_vector_type(4)));

// ====================== cooperative mega-kernel ======================
// Phases separated by grid.sync():
//   A : per-pixel channel avg/max (read x #1); block0 zeroes accumulators
//   B1: 7x7 conv(avg,max)+sigmoid -> sa_map; mask byte
//   B2: 7x7 convs on sa_map -> gamma,beta
//   C : per-channel masked/unmasked sums (read x #2) + mask count (c==0 tasks)
//   D : per-channel affine coefs (uniform per block) + final (read x #3, write out)
__global__ void __launch_bounds__(NTHR_, 2)
k_mega(const float* __restrict__ x,
       const float* __restrict__ w1, const float* __restrict__ wg,
       const float* __restrict__ bgp, const float* __restrict__ wb,
       const float* __restrict__ bbp,
       float* __restrict__ avgp, float* __restrict__ maxp,
       float* __restrict__ samap, float* __restrict__ gammap,
       float* __restrict__ betap,
       float* __restrict__ acc,            // [257]: S(64) Q(64) S1(64) Q1(64) cntf(1)
       unsigned char* __restrict__ maskp,
       float* __restrict__ out)
{
    cg::grid_group grid = cg::this_grid();
    const int tid = blockIdx.x * NTHR_ + threadIdx.x;

    __shared__ float w[196];                 // w1(98) | wg(49) | wb(49)
    if (threadIdx.x < 98) w[threadIdx.x] = w1[threadIdx.x];
    else if (threadIdx.x < 147) w[threadIdx.x] = wg[threadIdx.x - 98];
    else if (threadIdx.x < 196) w[threadIdx.x] = wb[threadIdx.x - 147];

    if (blockIdx.x == 0 && threadIdx.x < 257) acc[threadIdx.x] = 0.f;

    // ---------------- Phase A: channel avg/max (tid covers PIX_/4 exactly) -------
    {
        int idx4 = tid * 4;
        int b = idx4 >> 16;
        int p = idx4 & (PLANE_ - 1);
        const float* xb = x + (size_t)b * C_ * PLANE_ + p;
        float4 s = make_float4(0.f, 0.f, 0.f, 0.f);
        float4 mx = make_float4(-INFINITY, -INFINITY, -INFINITY, -INFINITY);
        #pragma unroll 8
        for (int c = 0; c < C_; ++c) {
            float4 v = *(const float4*)(xb + (size_t)c * PLANE_);
            s.x += v.x; s.y += v.y; s.z += v.z; s.w += v.w;
            mx.x = fmaxf(mx.x, v.x); mx.y = fmaxf(mx.y, v.y);
            mx.z = fmaxf(mx.z, v.z); mx.w = fmaxf(mx.w, v.w);
        }
        const float r = 1.f / C_;
        s.x *= r; s.y *= r; s.z *= r; s.w *= r;
        *(float4*)(avgp + idx4) = s;
        *(float4*)(maxp + idx4) = mx;
    }
    grid.sync();

    // ---------------- Phase B1: sa conv + sigmoid + mask ----------------
    for (int px = tid; px < PIX_; px += NTID_) {
        int b = px >> 16;
        int r = px & (PLANE_ - 1);
        int i = r >> 8;
        int j = r & (N_ - 1);
        const float* a = avgp + (size_t)b * PLANE_;
        const float* m = maxp + (size_t)b * PLANE_;
        float acc_ = 0.f;
        #pragma unroll
        for (int dh = 0; dh < 7; ++dh) {
            int ii = i + dh - 3;
            if ((unsigned)ii >= (unsigned)M_) continue;
            #pragma unroll
            for (int dw = 0; dw < 7; ++dw) {
                int jj = j + dw - 3;
                if ((unsigned)jj >= (unsigned)N_) continue;
                int o = ii * N_ + jj;
                acc_ += a[o] * w[dh * 7 + dw] + m[o] * w[49 + dh * 7 + dw];
            }
        }
        float sa = 1.f / (1.f + expf(-acc_));
        samap[px] = sa;
        maskp[px] = (unsigned char)(sa >= THRESH_ ? 1 : 0);
    }
    grid.sync();

    // ---------------- Phase B2: gamma/beta convs ----------------
    {
        float bgv = bgp[0], bbv = bbp[0];
        for (int px = tid; px < PIX_; px += NTID_) {
            int b = px >> 16;
            int r = px & (PLANE_ - 1);
            int i = r >> 8;
            int j = r & (N_ - 1);
            const float* s = samap + (size_t)b * PLANE_;
            float g = 0.f, be = 0.f;
            #pragma unroll
            for (int dh = 0; dh < 7; ++dh) {
                int ii = i + dh - 3;
                if ((unsigned)ii >= (unsigned)M_) continue;
                #pragma unroll
                for (int dw = 0; dw < 7; ++dw) {
                    int jj = j + dw - 3;
                    if ((unsigned)jj >= (unsigned)N_) continue;
                    float v = s[ii * N_ + jj];
                    g  += v * w[98 + dh * 7 + dw];
                    be += v * w[147 + dh * 7 + dw];
                }
            }
            gammap[px] = g + bgv;
            betap[px]  = be + bbv;
        }
    }

    // ------- Phase C: per-channel sums (+ mask count on c==0 tasks) -------
    {
        __shared__ float ls[4][5];
        for (int t = blockIdx.x; t < B_ * C_ * 8; t += NBLK_) {       // 8 tasks/block
            int c = t & 63, chunk = (t >> 6) & 7, b = t >> 9;
            const float* xp = x + ((size_t)(b * C_ + c)) * PLANE_ + chunk * 8192;
            const unsigned char* mp = maskp + (size_t)b * PLANE_ + chunk * 8192;
            float s = 0.f, q = 0.f, s1 = 0.f, q1 = 0.f, cn = 0.f;
            #pragma unroll
            for (int k = 0; k < 8; ++k) {
                int o = (k * 256 + threadIdx.x) * 4;
                float4 v = *(const float4*)(xp + o);
                uchar4 mm = *(const uchar4*)(mp + o);
                float m0 = (float)mm.x, m1 = (float)mm.y, m2 = (float)mm.z, m3 = (float)mm.w;
                s  += v.x + v.y + v.z + v.w;
                q  += v.x * v.x + v.y * v.y + v.z * v.z + v.w * v.w;
                s1 += v.x * m0 + v.y * m1 + v.z * m2 + v.w * m3;
                q1 += v.x * v.x * m0 + v.y * v.y * m1 + v.z * v.z * m2 + v.w * v.w * m3;
                cn += m0 + m1 + m2 + m3;
            }
            for (int off = 32; off > 0; off >>= 1) {
                s  += __shfl_down(s, off, 64);
                q  += __shfl_down(q, off, 64);
                s1 += __shfl_down(s1, off, 64);
                q1 += __shfl_down(q1, off, 64);
                cn += __shfl_down(cn, off, 64);
            }
            int wave = threadIdx.x >> 6, lane = threadIdx.x & 63;
            if (lane == 0) {
                ls[wave][0] = s; ls[wave][1] = q; ls[wave][2] = s1;
                ls[wave][3] = q1; ls[wave][4] = cn;
            }
            __syncthreads();
            if (threadIdx.x == 0) {
                float ts = 0.f, tq = 0.f, ts1 = 0.f, tq1 = 0.f, tc = 0.f;
                #pragma unroll
                for (int wv = 0; wv < 4; ++wv) {
                    ts += ls[wv][0]; tq += ls[wv][1]; ts1 += ls[wv][2];
                    tq1 += ls[wv][3]; tc += ls[wv][4];
                }
                atomicAdd(&acc[c], ts); atomicAdd(&acc[64 + c], tq);
                atomicAdd(&acc[128 + c], ts1); atomicAdd(&acc[192 + c], tq1);
                if (c == 0) atomicAdd(&acc[256], tc);
            }
            __syncthreads();
        }
    }
    __threadfence();
    grid.sync();

    // -------- Phase D: coefs (uniform per block, c fixed) + final --------
    {
        int c = blockIdx.x & 63;            // stride NBLK_ (mult of 64) keeps c fixed
        const float P = (float)PIX_;
        float cntf = acc[256];
        int cnt1 = (int)cntf;
        float fc1 = cntf;
        float fc0 = P - fc1;
        float Sr1 = (cnt1 == 0) ? 1.f : fc1;
        float Sr0 = (cnt1 == PIX_) ? 1.f : fc0;
        float Sv = acc[c], Qv = acc[64 + c], S1v = acc[128 + c], Q1v = acc[192 + c];
        float S0v = Sv - S1v, Q0v = Qv - Q1v;
        float mu1 = S1v / Sr1;
        float mu0 = S0v / Sr0;
        float m1 = (S1v + fc0 * mu1) / P;
        float v1 = fmaxf((Q1v + fc0 * mu1 * mu1) / P - m1 * m1, 0.f);
        float m0 = (S0v + fc1 * mu0) / P;
        float v0 = fmaxf((Q0v + fc1 * mu0 * mu0) / P - m0 * m0, 0.f);
        float A1 = rsqrtf(v1 + EPS_) * sqrtf(Sr1 / P);
        float A0 = rsqrtf(v0 + EPS_) * sqrtf(Sr0 / P);
        float B1c = (mu1 - m1) * A1;
        float B0c = (mu0 - m0) * A0;
        float ma = A1, mb = -m1 * A1 + B0c;   // masked
        float ua = A0, ub = -m0 * A0 + B1c;   // unmasked

        for (int t = blockIdx.x; t < B_ * C_ * 64; t += NBLK_) {      // 64 tasks/block
            int chunk = (t >> 6) & 63;
            int b = t >> 12;
            int p0 = chunk * 1024 + threadIdx.x * 4;
            size_t base = ((size_t)(b * C_ + c)) * PLANE_ + p0;
            int pp = b * PLANE_ + p0;
            float4 xv = *(const float4*)(x + base);
            float4 gv = *(const float4*)(gammap + pp);
            float4 bv = *(const float4*)(betap + pp);
            uchar4 mv = *(const uchar4*)(maskp + pp);
            vfloat4 o;
            o.x = (mv.x ? xv.x * ma + mb : xv.x * ua + ub) * (1.f + gv.x) + bv.x;
            o.y = (mv.y ? xv.y * ma + mb : xv.y * ua + ub) * (1.f + gv.y) + bv.y;
            o.z = (mv.z ? xv.z * ma + mb : xv.z * ua + ub) * (1.f + gv.z) + bv.z;
            o.w = (mv.w ? xv.w * ma + mb : xv.w * ua + ub) * (1.f + gv.w) + bv.w;
            __builtin_nontemporal_store(o, (vfloat4*)(out + base));
        }
    }
}

// ====================== fallback multi-kernel path (R3, proven) ======================
__global__ void k_avgmax(const float* __restrict__ x,
                         float* __restrict__ avgp, float* __restrict__ maxp) {
    int idx4 = (blockIdx.x * blockDim.x + threadIdx.x) * 4;
    int b = idx4 >> 16;
    int p = idx4 & (PLANE_ - 1);
    const float* xb = x + (size_t)b * C_ * PLANE_ + p;
    float4 s = make_float4(0.f, 0.f, 0.f, 0.f);
    float4 mx = make_float4(-INFINITY, -INFINITY, -INFINITY, -INFINITY);
    #pragma unroll 16
    for (int c = 0; c < C_; ++c) {
        float4 v = *(const float4*)(xb + (size_t)c * PLANE_);
        s.x += v.x; s.y += v.y; s.z += v.z; s.w += v.w;
        mx.x = fmaxf(mx.x, v.x); mx.y = fmaxf(mx.y, v.y);
        mx.z = fmaxf(mx.z, v.z); mx.w = fmaxf(mx.w, v.w);
    }
    const float r = 1.f / C_;
    s.x *= r; s.y *= r; s.z *= r; s.w *= r;
    *(float4*)(avgp + idx4) = s;
    *(float4*)(maxp + idx4) = mx;
}

__global__ void k_saconv(const float* __restrict__ avgp, const float* __restrict__ maxp,
                         const float* __restrict__ w1, float* __restrict__ samap,
                         unsigned char* __restrict__ maskp) {
    __shared__ float w[98];
    if (threadIdx.x < 98) w[threadIdx.x] = w1[threadIdx.x];
    __syncthreads();
    int idx = blockIdx.x * blockDim.x + threadIdx.x;
    int b = idx >> 16;
    int r = idx & (PLANE_ - 1);
    int i = r >> 8;
    int j = r & (N_ - 1);
    const float* a = avgp + (size_t)b * PLANE_;
    const float* m = maxp + (size_t)b * PLANE_;
    float acc = 0.f;
    #pragma unroll
    for (int dh = 0; dh < 7; ++dh) {
        int ii = i + dh - 3;
        if ((unsigned)ii >= (unsigned)M_) continue;
        #pragma unroll
        for (int dw = 0; dw < 7; ++dw) {
            int jj = j + dw - 3;
            if ((unsigned)jj >= (unsigned)N_) continue;
            int o = ii * N_ + jj;
            acc += a[o] * w[dh * 7 + dw] + m[o] * w[49 + dh * 7 + dw];
        }
    }
    float sa = 1.f / (1.f + expf(-acc));
    samap[idx] = sa;
    maskp[idx] = (unsigned char)(sa >= THRESH_ ? 1 : 0);
}

__global__ void k_gammabeta(const float* __restrict__ samap,
                            const float* __restrict__ wg, const float* __restrict__ bgp,
                            const float* __restrict__ wb, const float* __restrict__ bbp,
                            float* __restrict__ gammap, float* __restrict__ betap) {
    __shared__ float w[98];
    if (threadIdx.x < 49) w[threadIdx.x] = wg[threadIdx.x];
    else if (threadIdx.x < 98) w[threadIdx.x] = wb[threadIdx.x - 49];
    __syncthreads();
    int idx = blockIdx.x * blockDim.x + threadIdx.x;
    int b = idx >> 16;
    int r = idx & (PLANE_ - 1);
    int i = r >> 8;
    int j = r & (N_ - 1);
    const float* s = samap + (size_t)b * PLANE_;
    float g = 0.f, be = 0.f;
    #pragma unroll
    for (int dh = 0; dh < 7; ++dh) {
        int ii = i + dh - 3;
        if ((unsigned)ii >= (unsigned)M_) continue;
        #pragma unroll
        for (int dw = 0; dw < 7; ++dw) {
            int jj = j + dw - 3;
            if ((unsigned)jj >= (unsigned)N_) continue;
            float v = s[ii * N_ + jj];
            g  += v * w[dh * 7 + dw];
            be += v * w[49 + dh * 7 + dw];
        }
    }
    gammap[idx] = g + bgp[0];
    betap[idx]  = be + bbp[0];
}

__global__ void k_sums(const float* __restrict__ x, const unsigned char* __restrict__ maskp,
                       float* __restrict__ acc) {
    int c = blockIdx.x;
    int chunk = blockIdx.y;
    int b = blockIdx.z;
    const float* xp = x + ((size_t)(b * C_ + c)) * PLANE_ + chunk * 8192;
    const unsigned char* mp = maskp + (size_t)b * PLANE_ + chunk * 8192;
    float s = 0.f, q = 0.f, s1 = 0.f, q1 = 0.f, cn = 0.f;
    #pragma unroll
    for (int k = 0; k < 8; ++k) {
        int t = (k * 256 + threadIdx.x) * 4;
        float4 v = *(const float4*)(xp + t);
        uchar4 mm = *(const uchar4*)(mp + t);
        float m0 = (float)mm.x, m1 = (float)mm.y, m2 = (float)mm.z, m3 = (float)mm.w;
        s  += v.x + v.y + v.z + v.w;
        q  += v.x * v.x + v.y * v.y + v.z * v.z + v.w * v.w;
        s1 += v.x * m0 + v.y * m1 + v.z * m2 + v.w * m3;
        q1 += v.x * v.x * m0 + v.y * v.y * m1 + v.z * v.z * m2 + v.w * v.w * m3;
        cn += m0 + m1 + m2 + m3;
    }
    for (int off = 32; off > 0; off >>= 1) {
        s  += __shfl_down(s, off, 64);
        q  += __shfl_down(q, off, 64);
        s1 += __shfl_down(s1, off, 64);
        q1 += __shfl_down(q1, off, 64);
        cn += __shfl_down(cn, off, 64);
    }
    __shared__ float ls[4][5];
    int wave = threadIdx.x >> 6, lane = threadIdx.x & 63;
    if (lane == 0) { ls[wave][0] = s; ls[wave][1] = q; ls[wave][2] = s1; ls[wave][3] = q1; ls[wave][4] = cn; }
    __syncthreads();
    if (threadIdx.x == 0) {
        float ts = 0.f, tq = 0.f, ts1 = 0.f, tq1 = 0.f, tc = 0.f;
        #pragma unroll
        for (int wv = 0; wv < 4; ++wv) {
            ts += ls[wv][0]; tq += ls[wv][1]; ts1 += ls[wv][2]; tq1 += ls[wv][3]; tc += ls[wv][4];
        }
        atomicAdd(&acc[c], ts); atomicAdd(&acc[64 + c], tq);
        atomicAdd(&acc[128 + c], ts1); atomicAdd(&acc[192 + c], tq1);
        if (c == 0) atomicAdd(&acc[256], tc);
    }
}

__global__ void k_final(const float* __restrict__ x, const unsigned char* __restrict__ maskp,
                        const float* __restrict__ gammap, const float* __restrict__ betap,
                        const float* __restrict__ acc, float* __restrict__ out) {
    int c = blockIdx.x;
    int b = blockIdx.z;
    int p0 = blockIdx.y * 1024 + threadIdx.x * 4;

    const float P = (float)PIX_;
    float cntf = acc[256];
    int cnt1 = (int)cntf;
    float fc1 = cntf;
    float fc0 = P - fc1;
    float Sr1 = (cnt1 == 0) ? 1.f : fc1;
    float Sr0 = (cnt1 == PIX_) ? 1.f : fc0;
    float Sv = acc[c], Qv = acc[64 + c], S1v = acc[128 + c], Q1v = acc[192 + c];
    float S0v = Sv - S1v, Q0v = Qv - Q1v;
    float mu1 = S1v / Sr1;
    float mu0 = S0v / Sr0;
    float m1 = (S1v + fc0 * mu1) / P;
    float v1 = fmaxf((Q1v + fc0 * mu1 * mu1) / P - m1 * m1, 0.f);
    float m0 = (S0v + fc1 * mu0) / P;
    float v0 = fmaxf((Q0v + fc1 * mu0 * mu0) / P - m0 * m0, 0.f);
    float A1 = rsqrtf(v1 + EPS_) * sqrtf(Sr1 / P);
    float A0 = rsqrtf(v0 + EPS_) * sqrtf(Sr0 / P);
    float B1c = (mu1 - m1) * A1;
    float B0c = (mu0 - m0) * A0;
    float ma = A1, mb = -m1 * A1 + B0c;
    float ua = A0, ub = -m0 * A0 + B1c;

    size_t base = ((size_t)(b * C_ + c)) * PLANE_ + p0;
    int pp = b * PLANE_ + p0;
    float4 xv = *(const float4*)(x + base);
    float4 gv = *(const float4*)(gammap + pp);
    float4 bv = *(const float4*)(betap + pp);
    uchar4 mv = *(const uchar4*)(maskp + pp);
    vfloat4 o;
    o.x = (mv.x ? xv.x * ma + mb : xv.x * ua + ub) * (1.f + gv.x) + bv.x;
    o.y = (mv.y ? xv.y * ma + mb : xv.y * ua + ub) * (1.f + gv.y) + bv.y;
    o.z = (mv.z ? xv.z * ma + mb : xv.z * ua + ub) * (1.f + gv.z) + bv.z;
    o.w = (mv.w ? xv.w * ma + mb : xv.w * ua + ub) * (1.f + gv.w) + bv.w;
    __builtin_nontemporal_store(o, (vfloat4*)(out + base));
}

extern "C" void kernel_launch(void* const* d_in, const int* in_sizes, int n_in,
                              void* d_out, int out_size, void* d_ws, size_t ws_size,
                              hipStream_t stream) {
    const float* x  = (const float*)d_in[0];
    const float* w1 = (const float*)d_in[1];
    const float* wg = (const float*)d_in[2];
    const float* bg = (const float*)d_in[3];
    const float* wb = (const float*)d_in[4];
    const float* bb = (const float*)d_in[5];
    float* out = (float*)d_out;

    float* ws = (float*)d_ws;
    float* avgp   = ws;                       // PIX_
    float* maxp   = avgp + PIX_;              // PIX_
    float* samap  = maxp + PIX_;              // PIX_
    float* gammap = samap + PIX_;             // PIX_
    float* betap  = gammap + PIX_;            // PIX_
    float* acc    = betap + PIX_;             // 257 (+pad to 260 for alignment)
    unsigned char* maskp = (unsigned char*)(acc + 260);  // PIX_ bytes

    void* args[] = { (void*)&x, (void*)&w1, (void*)&wg, (void*)&bg, (void*)&wb, (void*)&bb,
                     (void*)&avgp, (void*)&maxp, (void*)&samap, (void*)&gammap, (void*)&betap,
                     (void*)&acc, (void*)&maskp, (void*)&out };
    hipError_t e = hipLaunchCooperativeKernel((const void*)k_mega, dim3(NBLK_), dim3(NTHR_),
                                              args, 0, stream);
    if (e != hipSuccess) {
        // deterministic fallback: proven multi-kernel path
        (void)hipMemsetAsync(acc, 0, 257 * sizeof(float), stream);
        k_avgmax<<<PIX_ / (256 * 4), 256, 0, stream>>>(x, avgp, maxp);
        k_saconv<<<PIX_ / 256, 256, 0, stream>>>(avgp, maxp, w1, samap, maskp);
        k_gammabeta<<<PIX_ / 256, 256, 0, stream>>>(samap, wg, bg, wb, bb, gammap, betap);
        dim3 g3(C_, 8, B_);
        k_sums<<<g3, 256, 0, stream>>>(x, maskp, acc);
        dim3 g5(C_, PLANE_ / 1024, B_);
        k_final<<<g5, 256, 0, stream>>>(x, maskp, gammap, betap, acc, out);
    }
}